// Round 5
// baseline (444.141 us; speedup 1.0000x reference)
//
#include <hip/hip_runtime.h>

// MultiBoxLoss_four_corners — B=64, P=8732, C=81, NEG_POS_RATIO=3
// Outputs: (loss_l/N, loss_c/N, loss_four_corners/N) -> d_out[0..2] (f32)
//
// R5: every global read is lane-consecutive coalesced. conf rows are staged
// tile-wise (64 rows = 5184 floats = 20.7 KB) into LDS by 512-thread blocks
// that LOOP over ~4-5 tiles (R3's one-shot tiny blocks paid ~19K cycles of
// churn per block; R2/R4's direct-read patterns put 64 distinct lines under
// every load inst and plateau at 1500 GB/s). 4 blocks/CU resident = 32
// waves/CU; cross-block stagger hides the barrier drains. CE from LDS with
// 8 threads/row; per-batch sums via LDS atomics flushed once per block.

#define NB 64
#define NP 8732
#define NC 81
constexpr int BP     = NB * NP;        // 558848 rows
constexpr int NTILES = BP / 64;        // 8732 tiles of 64 rows (exact)
constexpr int GRID   = 2048;
constexpr int BLK    = 512;
constexpr int TOTTHR = GRID * BLK;     // 1,048,576

__device__ inline float sl1(float d) {
    d = fabsf(d);
    return d < 1.0f ? 0.5f * d * d : d - 0.5f;
}

// ws: ce[BP] | acc[64] (l:0..31, f:32..63) | gb[192] (sp:0..63, sn:64..127,
//     np:128..191) | loss_c_b[64]
__global__ void k_init(float* z) {         // zero acc[64] + gb[192]
    z[threadIdx.x] = 0.0f;                 // 256 threads
}

__global__ __launch_bounds__(BLK, 8) void k_main(
    const float* __restrict__ loc_data, const float* __restrict__ conf_data,
    const float* __restrict__ fc_data,  const float* __restrict__ loc_t,
    const float* __restrict__ fc_t,     const int* __restrict__ conf_t,
    float* __restrict__ ce, float* __restrict__ acc, float* __restrict__ gb)
{
    __shared__ float conf_s[64 * NC];      // 20736 B
    __shared__ int   tgt_s[64];
    __shared__ float lds_acc[192];         // sp[64] | sn[64] | np[64]

    const int t    = threadIdx.x;
    const int lane = t & 63;
    const int gtid = blockIdx.x * BLK + t;

    // zero per-block batch accumulators (first stage barrier orders this)
    if (t < 192) lds_acc[t] = 0.0f;

    // ---- conf CE: loop over tiles of 64 rows ----
    for (int tile = blockIdx.x; tile < NTILES; tile += GRID) {
        // stage: lane-consecutive float4 (fully coalesced), 2-3 per thread
        const float4* src = (const float4*)conf_data + (size_t)tile * 1296;
        #pragma unroll
        for (int k = 0; k < 3; ++k) {
            const int i = k * BLK + t;
            if (i < 1296) ((float4*)conf_s)[i] = src[i];
        }
        if (t < 16) ((int4*)tgt_s)[t] = ((const int4*)(conf_t + tile * 64))[t];
        __syncthreads();

        // compute: 8 threads per row, 10(+1) exps each, combine via shuffles
        const int r = t >> 3;              // 0..63
        const int o = t & 7;               // 0..7
        const float* rowp = conf_s + r * NC;
        const float* cp = rowp + o * 10;
        float s = 0.0f;
        #pragma unroll
        for (int j = 0; j < 10; ++j) s += __expf(cp[j]);
        if (o == 7) s += __expf(rowp[80]);
        s += __shfl_xor(s, 1, 64);
        s += __shfl_xor(s, 2, 64);
        s += __shfl_xor(s, 4, 64);
        if (o == 0) {
            const int row = tile * 64 + r;
            const int tgt = tgt_s[r];
            const float cev = __logf(s) - rowp[tgt];
            ce[row] = cev;
            const int b = row / NP;
            if (tgt > 0) {
                atomicAdd(&lds_acc[b], cev);           // sp
                atomicAdd(&lds_acc[128 + b], 1.0f);    // np
            } else {
                atomicAdd(&lds_acc[64 + b], cev);      // sn
            }
        }
        __syncthreads();                   // LDS free for next tile
    }

    // ---- loc/fc smooth-L1: coalesced grid-stride float4 ----
    float l_acc = 0.0f, f_acc = 0.0f;
    for (int i = gtid; i < BP; i += TOTTHR) {          // loc: f4 index == row
        float4 a = ((const float4*)loc_data)[i];
        float4 b = ((const float4*)loc_t)[i];
        float m = (conf_t[i] > 0) ? 1.0f : 0.0f;
        l_acc += m * (sl1(a.x - b.x) + sl1(a.y - b.y) + sl1(a.z - b.z) + sl1(a.w - b.w));
    }
    for (int i = gtid; i < 2 * BP; i += TOTTHR) {      // fc: row = i >> 1
        float4 a = ((const float4*)fc_data)[i];
        float4 b = ((const float4*)fc_t)[i];
        float m = (conf_t[i >> 1] > 0) ? 1.0f : 0.0f;
        f_acc += m * (sl1(a.x - b.x) + sl1(a.y - b.y) + sl1(a.z - b.z) + sl1(a.w - b.w));
    }
    #pragma unroll
    for (int o2 = 32; o2; o2 >>= 1) {
        l_acc += __shfl_xor(l_acc, o2, 64);
        f_acc += __shfl_xor(f_acc, o2, 64);
    }
    if (lane == 0) {
        const int slot = blockIdx.x & 31;
        atomicAdd(&acc[slot],      l_acc);
        atomicAdd(&acc[32 + slot], f_acc);
    }

    // ---- flush per-block batch sums ----
    __syncthreads();
    if (t < 192) {
        float v = lds_acc[t];
        if (v != 0.0f) atomicAdd(&gb[t], v);
    }
}

// One block per batch. Common path O(1); rare top-K via float-bit binary search.
__global__ __launch_bounds__(256) void k_batch(
    const float* __restrict__ ce, const int* __restrict__ conf_t,
    const float* __restrict__ gb, float* __restrict__ loss_c_b)
{
    const int b = blockIdx.x;
    const int t = threadIdx.x;
    const float spos = gb[b];
    const float sneg = gb[64 + b];
    const int npos    = (int)(gb[128 + b] + 0.5f);
    const int nneg    = NP - npos;
    const int num_neg = min(3 * npos, NP - 1);

    if (num_neg >= nneg) {                 // all negatives selected (this data)
        if (t == 0) loss_c_b[b] = spos + sneg;
        return;
    }
    if (num_neg <= 0) {
        if (t == 0) loss_c_b[b] = spos;
        return;
    }

    __shared__ float ce_s[NP];             // negative CE; positives -> -1
    __shared__ float sredf[4];
    __shared__ int   sredi[4];
    const float* crow = ce + (size_t)b * NP;
    const int*   trow = conf_t + (size_t)b * NP;
    for (int p = t; p < NP; p += 256)
        ce_s[p] = (trow[p] > 0) ? -1.0f : crow[p];
    __syncthreads();

    const int wave = t >> 6, lane = t & 63;
    const int K = num_neg;
    unsigned lo = 0u, hi = 0x7f800000u;
    while (lo < hi) {
        unsigned mid = lo + ((hi - lo) >> 1);
        float v = __uint_as_float(mid);
        int c_t = 0;
        for (int p = t; p < NP; p += 256) c_t += (ce_s[p] > v) ? 1 : 0;
        #pragma unroll
        for (int o = 32; o; o >>= 1) c_t += __shfl_xor(c_t, o, 64);
        __syncthreads();
        if (lane == 0) sredi[wave] = c_t;
        __syncthreads();
        int cnt = sredi[0] + sredi[1] + sredi[2] + sredi[3];
        if (cnt < K) hi = mid; else lo = mid + 1;
    }
    float v = __uint_as_float(lo);         // K-th largest negative CE
    int c_t = 0; float s_t = 0.0f;
    for (int p = t; p < NP; p += 256) {
        float x = ce_s[p];
        if (x > v) { c_t++; s_t += x; }
    }
    #pragma unroll
    for (int o = 32; o; o >>= 1) {
        c_t += __shfl_xor(c_t, o, 64);
        s_t += __shfl_xor(s_t, o, 64);
    }
    __syncthreads();
    if (lane == 0) { sredi[wave] = c_t; sredf[wave] = s_t; }
    __syncthreads();
    if (t == 0) {
        int   cnt = sredi[0] + sredi[1] + sredi[2] + sredi[3];
        float sgt = sredf[0] + sredf[1] + sredf[2] + sredf[3];
        loss_c_b[b] = spos + sgt + (float)(K - cnt) * v;
    }
}

__global__ void k_final(const float* __restrict__ acc,
                        const float* __restrict__ gb,
                        const float* __restrict__ loss_c_b,
                        float* __restrict__ out)
{
    const int t = threadIdx.x;             // 64
    const float av = acc[t];
    float a0 = (t < 32) ? av : 0.0f;       // l-slots
    float a1 = av - a0;                    // f-slots
    float lc = loss_c_b[t];
    float np = gb[128 + t];
    #pragma unroll
    for (int o = 32; o; o >>= 1) {
        a0 += __shfl_xor(a0, o, 64);
        a1 += __shfl_xor(a1, o, 64);
        lc += __shfl_xor(lc, o, 64);
        np += __shfl_xor(np, o, 64);
    }
    if (t == 0) {
        out[0] = a0 / np;
        out[1] = lc / np;
        out[2] = a1 / np;
    }
}

extern "C" void kernel_launch(void* const* d_in, const int* in_sizes, int n_in,
                              void* d_out, int out_size, void* d_ws, size_t ws_size,
                              hipStream_t stream)
{
    const float* loc_data  = (const float*)d_in[0];
    const float* conf_data = (const float*)d_in[1];
    const float* fc_data   = (const float*)d_in[2];
    const float* loc_t     = (const float*)d_in[3];
    const float* fc_t      = (const float*)d_in[4];
    const int*   conf_t    = (const int*)d_in[5];
    float* out = (float*)d_out;

    float* ce       = (float*)d_ws;
    float* acc      = ce + BP;             // [64]
    float* gb       = acc + 64;            // [192]
    float* loss_c_b = gb + 192;            // [64]

    hipLaunchKernelGGL(k_init,  dim3(1),    dim3(256), 0, stream, acc);
    hipLaunchKernelGGL(k_main,  dim3(GRID), dim3(BLK), 0, stream,
                       loc_data, conf_data, fc_data, loc_t, fc_t, conf_t,
                       ce, acc, gb);
    hipLaunchKernelGGL(k_batch, dim3(NB),   dim3(256), 0, stream,
                       ce, conf_t, gb, loss_c_b);
    hipLaunchKernelGGL(k_final, dim3(1),    dim3(64),  0, stream,
                       acc, gb, loss_c_b, out);
}